// Round 1
// baseline (260.829 us; speedup 1.0000x reference)
//
#include <hip/hip_runtime.h>
#include <stdint.h>

// Problem constants
#define SEQ   2048
#define DEMB  1024
#define NH    16
#define HD    64
#define MROWS 4096   // BS*SEQ

typedef __bf16 bf16x8 __attribute__((ext_vector_type(8)));
typedef float  f32x4  __attribute__((ext_vector_type(4)));

#define MFMA(a, b, c) __builtin_amdgcn_mfma_f32_16x16x32_bf16((a), (b), (c), 0, 0, 0)

static __device__ __forceinline__ uint16_t f2bf(float f) {
  uint32_t u = __float_as_uint(f);
  u += 0x7FFFu + ((u >> 16) & 1u);   // RNE
  return (uint16_t)(u >> 16);
}

static __device__ __forceinline__ bf16x8 ldb8(const uint16_t* p) {
  union { uint4 i; bf16x8 b; } u;
  u.i = *(const uint4*)p;
  return u.b;
}

static __device__ __forceinline__ void gld_lds16(const uint16_t* g, uint16_t* l) {
  __builtin_amdgcn_global_load_lds(
      (const __attribute__((address_space(1))) uint32_t*)(g),
      (__attribute__((address_space(3))) uint32_t*)(l),
      16, 0, 0);
}

// ---------------------------------------------------------------- converts
__global__ __launch_bounds__(256) void cvt_f32_bf16(const float* __restrict__ in,
                                                    uint16_t* __restrict__ out) {
  int i = (blockIdx.x * 256 + threadIdx.x) * 4;
  float4 v = *(const float4*)(in + i);
  ushort4 o;
  o.x = f2bf(v.x); o.y = f2bf(v.y); o.z = f2bf(v.z); o.w = f2bf(v.w);
  *(ushort4*)(out + i) = o;
}

// ---------------------------------------------------------------- GEMM C = A * B^T
// A: MxK bf16 row-major, B: NxK bf16 row-major. M,N mult of 128, K mult of 32.
// MODE 0: bf16 out (scaled).  MODE 1: per-head transposed V out (b,h,d,s).
// MODE 2: fp32 out + bias.
template <int MODE>
__global__ __launch_bounds__(256) void gemm_bt(const uint16_t* __restrict__ A,
                                               const uint16_t* __restrict__ B,
                                               uint16_t* __restrict__ Cb,
                                               float* __restrict__ Cf,
                                               const float* __restrict__ bias,
                                               int M, int N, int K, float scale) {
  __shared__ uint16_t As[128 * 32];
  __shared__ uint16_t Bs[128 * 32];
  const int t  = threadIdx.x;
  const int l  = t & 63;
  const int li = l & 15, lg = l >> 4;
  const int w  = t >> 6;
  const int wr = (w >> 1) << 6, wc = (w & 1) << 6;
  const int brow = blockIdx.y << 7, bcol = blockIdx.x << 7;

  const uint16_t* ga0 = A + (size_t)(brow + (t >> 2)) * K + (t & 3) * 8;
  const uint16_t* ga1 = ga0 + (size_t)64 * K;
  const uint16_t* gb0 = B + (size_t)(bcol + (t >> 2)) * K + (t & 3) * 8;
  const uint16_t* gb1 = gb0 + (size_t)64 * K;

  f32x4 acc[4][4] = {};

  for (int k0 = 0; k0 < K; k0 += 32) {
    __syncthreads();                       // all waves done reading previous tile
    gld_lds16(ga0 + k0, &As[t * 8]);       // rows 0..63   (LDS bytes t*16)
    gld_lds16(ga1 + k0, &As[2048 + t * 8]);// rows 64..127
    gld_lds16(gb0 + k0, &Bs[t * 8]);
    gld_lds16(gb1 + k0, &Bs[2048 + t * 8]);
    __syncthreads();                       // compiler drains vmcnt before barrier

    bf16x8 af[4], bfr[4];
#pragma unroll
    for (int i = 0; i < 4; ++i)
      af[i] = ldb8(&As[(wr + i * 16 + li) * 32 + lg * 8]);
#pragma unroll
    for (int i = 0; i < 4; ++i)
      bfr[i] = ldb8(&Bs[(wc + i * 16 + li) * 32 + lg * 8]);
#pragma unroll
    for (int mi = 0; mi < 4; ++mi)
#pragma unroll
      for (int ni = 0; ni < 4; ++ni)
        acc[mi][ni] = MFMA(af[mi], bfr[ni], acc[mi][ni]);
  }

#pragma unroll
  for (int mi = 0; mi < 4; ++mi) {
#pragma unroll
    for (int ni = 0; ni < 4; ++ni) {
      const int row = brow + wr + mi * 16 + lg * 4;   // + r
      const int col = bcol + wc + ni * 16 + li;
#pragma unroll
      for (int r = 0; r < 4; ++r) {
        const float v = acc[mi][ni][r];
        if (MODE == 0) {
          Cb[(size_t)(row + r) * N + col] = f2bf(v * scale);
        } else if (MODE == 1) {
          const int m = row + r;                      // m = b*2048 + s
          Cb[((size_t)col + (size_t)((m >> 11) << 10)) * 2048 + (m & 2047)] = f2bf(v);
        } else {
          Cf[(size_t)(row + r) * N + col] = v + bias[col];
        }
      }
    }
  }
}

// ---------------------------------------------------------------- flash attention
// Q,K: (4096 x 1024) bf16 row-major (Q pre-scaled by 1/8). Vt: (b,h,d,s) bf16.
// ctx out: (4096 x 1024) bf16 row-major.
__global__ __launch_bounds__(256) void attn_fwd(const uint16_t* __restrict__ Q,
                                                const uint16_t* __restrict__ K,
                                                const uint16_t* __restrict__ Vt,
                                                uint16_t* __restrict__ ctx) {
  const int bh = blockIdx.x;           // 0..31
  const int qb = 31 - blockIdx.y;      // heavy q-blocks dispatched first
  const int b  = bh >> 4, h = bh & 15;
  const int t  = threadIdx.x;
  const int w  = t >> 6, l = t & 63;
  const int li = l & 15, lg = l >> 4;

  __shared__ uint16_t P[4][16][72];    // per-wave private P slab (padded rows)

  const int qrow = (qb << 6) + (w << 4);                   // within seq
  const uint16_t* qp = Q + (size_t)(b * 2048 + qrow + li) * 1024 + h * 64 + lg * 8;
  const bf16x8 aq0 = ldb8(qp);
  const bf16x8 aq1 = ldb8(qp + 32);

  f32x4 o[4] = {};
  float m_r[4] = {-1e30f, -1e30f, -1e30f, -1e30f};
  float l_r[4] = {0.f, 0.f, 0.f, 0.f};

  for (int kt = 0; kt <= qb; ++kt) {
    const int kbase = kt << 6;
    const uint16_t* kp = K + (size_t)(b * 2048 + kbase + li) * 1024 + h * 64 + lg * 8;

    f32x4 s[4];
#pragma unroll
    for (int tt = 0; tt < 4; ++tt) {
      f32x4 z = {};
      z = MFMA(aq0, ldb8(kp + (size_t)tt * 16 * 1024), z);
      z = MFMA(aq1, ldb8(kp + (size_t)tt * 16 * 1024 + 32), z);
      s[tt] = z;   // col(li)=key, row(lg*4+r)=q
    }

    if (kt == qb) {   // diagonal tile: causal mask
#pragma unroll
      for (int tt = 0; tt < 4; ++tt) {
        const int key = (tt << 4) + li;
#pragma unroll
        for (int r = 0; r < 4; ++r) {
          const int qr = (w << 4) + lg * 4 + r;
          if (key > qr) s[tt][r] = -1e30f;
        }
      }
    }

#pragma unroll
    for (int r = 0; r < 4; ++r) {
      float tm = fmaxf(fmaxf(s[0][r], s[1][r]), fmaxf(s[2][r], s[3][r]));
      tm = fmaxf(tm, __shfl_xor(tm, 1));
      tm = fmaxf(tm, __shfl_xor(tm, 2));
      tm = fmaxf(tm, __shfl_xor(tm, 4));
      tm = fmaxf(tm, __shfl_xor(tm, 8));
      const float mn = fmaxf(m_r[r], tm);
      const float corr = __expf(m_r[r] - mn);
      m_r[r] = mn;
      float sum = 0.f;
#pragma unroll
      for (int tt = 0; tt < 4; ++tt) {
        const float p = __expf(s[tt][r] - mn);
        s[tt][r] = p;
        sum += p;
      }
      sum += __shfl_xor(sum, 1);
      sum += __shfl_xor(sum, 2);
      sum += __shfl_xor(sum, 4);
      sum += __shfl_xor(sum, 8);
      l_r[r] = l_r[r] * corr + sum;
#pragma unroll
      for (int dt = 0; dt < 4; ++dt) o[dt][r] *= corr;
    }

    // P -> per-wave LDS (relayout for PV A-operand)
#pragma unroll
    for (int tt = 0; tt < 4; ++tt)
#pragma unroll
      for (int r = 0; r < 4; ++r)
        P[w][lg * 4 + r][tt * 16 + li] = f2bf(s[tt][r]);
    asm volatile("s_waitcnt lgkmcnt(0)" ::: "memory");

    const bf16x8 pa0 = ldb8(&P[w][li][lg * 8]);        // q=li, keys 0..31
    const bf16x8 pa1 = ldb8(&P[w][li][32 + lg * 8]);   // keys 32..63
    const uint16_t* vp = Vt + (size_t)(b * 1024 + h * 64 + li) * 2048 + kbase + lg * 8;
#pragma unroll
    for (int dt = 0; dt < 4; ++dt) {
      o[dt] = MFMA(pa0, ldb8(vp + (size_t)dt * 16 * 2048), o[dt]);
      o[dt] = MFMA(pa1, ldb8(vp + (size_t)dt * 16 * 2048 + 32), o[dt]);
    }
  }

#pragma unroll
  for (int dt = 0; dt < 4; ++dt)
#pragma unroll
    for (int r = 0; r < 4; ++r) {
      const int qg = b * 2048 + qrow + lg * 4 + r;
      ctx[(size_t)qg * 1024 + h * 64 + dt * 16 + li] = f2bf(o[dt][r] / l_r[r]);
    }
}

// ---------------------------------------------------------------- launch
extern "C" void kernel_launch(void* const* d_in, const int* in_sizes, int n_in,
                              void* d_out, int out_size, void* d_ws, size_t ws_size,
                              hipStream_t stream) {
  const float* x  = (const float*)d_in[0];
  const float* Wq = (const float*)d_in[1];
  const float* Wk = (const float*)d_in[2];
  const float* Wv = (const float*)d_in[3];
  const float* Wo = (const float*)d_in[4];
  const float* bo = (const float*)d_in[5];
  float* out = (float*)d_out;

  char* ws = (char*)d_ws;
  uint16_t* xb  = (uint16_t*)(ws);                          // 8MB (dead after V gemm)
  uint16_t* Wqb = (uint16_t*)(ws + ( 8u << 20));            // 2MB
  uint16_t* Wkb = (uint16_t*)(ws + (10u << 20));
  uint16_t* Wvb = (uint16_t*)(ws + (12u << 20));
  uint16_t* Wob = (uint16_t*)(ws + (14u << 20));
  uint16_t* Qb  = (uint16_t*)(ws + (16u << 20));            // 8MB
  uint16_t* Kb  = (uint16_t*)(ws + (24u << 20));            // 8MB
  uint16_t* Vt  = (uint16_t*)(ws + (32u << 20));            // 8MB
  uint16_t* Ctx = (uint16_t*)(ws);                          // overlays xb

  cvt_f32_bf16<<<4096, 256, 0, stream>>>(x,  xb);
  cvt_f32_bf16<<<1024, 256, 0, stream>>>(Wq, Wqb);
  cvt_f32_bf16<<<1024, 256, 0, stream>>>(Wk, Wkb);
  cvt_f32_bf16<<<1024, 256, 0, stream>>>(Wv, Wvb);
  cvt_f32_bf16<<<1024, 256, 0, stream>>>(Wo, Wob);

  dim3 gg(8, 32);
  // Q pre-scaled by 1/sqrt(HD)=0.125 (exact pow2, lossless in bf16)
  gemm_bt<0><<<gg, 256, 0, stream>>>(xb, Wqb, Qb, nullptr, nullptr, MROWS, 1024, 1024, 0.125f);
  gemm_bt<0><<<gg, 256, 0, stream>>>(xb, Wkb, Kb, nullptr, nullptr, MROWS, 1024, 1024, 1.0f);
  gemm_bt<1><<<gg, 256, 0, stream>>>(xb, Wvb, Vt, nullptr, nullptr, MROWS, 1024, 1024, 1.0f);

  attn_fwd<<<dim3(32, 32), 256, 0, stream>>>(Qb, Kb, Vt, Ctx);

  gemm_bt<2><<<gg, 256, 0, stream>>>(Ctx, Wob, nullptr, out, bo, MROWS, 1024, 1024, 1.0f);
}

// Round 2
// 233.663 us; speedup vs baseline: 1.1163x; 1.1163x over previous
//
#include <hip/hip_runtime.h>
#include <stdint.h>

#define SEQ   2048
#define DEMB  1024
#define NH    16
#define HD    64
#define MROWS 4096   // BS*SEQ

typedef __bf16 bf16x8 __attribute__((ext_vector_type(8)));
typedef float  f32x4  __attribute__((ext_vector_type(4)));

#define MFMA(a, b, c) __builtin_amdgcn_mfma_f32_16x16x32_bf16((a), (b), (c), 0, 0, 0)

static __device__ __forceinline__ uint16_t f2bf(float f) {
  uint32_t u = __float_as_uint(f);
  u += 0x7FFFu + ((u >> 16) & 1u);   // RNE
  return (uint16_t)(u >> 16);
}

static __device__ __forceinline__ bf16x8 ldb8(const uint16_t* p) {
  union { uint4 i; bf16x8 b; } u;
  u.i = *(const uint4*)p;
  return u.b;
}

static __device__ __forceinline__ void gld_lds16(const uint16_t* g, uint16_t* l) {
  __builtin_amdgcn_global_load_lds(
      (const __attribute__((address_space(1))) uint32_t*)(g),
      (__attribute__((address_space(3))) uint32_t*)(l),
      16, 0, 0);
}

// ---------------------------------------------------------------- converts
__global__ __launch_bounds__(256) void cvt_f32_bf16(const float* __restrict__ in,
                                                    uint16_t* __restrict__ out) {
  int i = (blockIdx.x * 256 + threadIdx.x) * 4;
  float4 v = *(const float4*)(in + i);
  ushort4 o;
  o.x = f2bf(v.x); o.y = f2bf(v.y); o.z = f2bf(v.z); o.w = f2bf(v.w);
  *(ushort4*)(out + i) = o;
}

// ---------------------------------------------------------------- GEMM C = A * B^T
// A: MxK bf16 row-major, B: NxK bf16 row-major (m97 structure, 128x128 tile).
// MODE 0: fused QKV epilogue (N=3072): cols [0,1024) -> Q (scaled 1/8),
//         [1024,2048) -> K, [2048,3072) -> V transposed per head (b,h,d,s).
// MODE 2: fp32 out + bias (out projection).
template <int MODE>
__global__ __launch_bounds__(256) void gemm_bt(const uint16_t* __restrict__ A,
                                               const uint16_t* __restrict__ B,
                                               uint16_t* __restrict__ Cq,
                                               uint16_t* __restrict__ Ck,
                                               uint16_t* __restrict__ Cvt,
                                               float* __restrict__ Cf,
                                               const float* __restrict__ bias,
                                               int K) {
  __shared__ uint16_t As[128 * 32];
  __shared__ uint16_t Bs[128 * 32];
  const int t  = threadIdx.x;
  const int l  = t & 63;
  const int li = l & 15, lg = l >> 4;
  const int w  = t >> 6;
  const int wr = (w >> 1) << 6, wc = (w & 1) << 6;
  const int brow = blockIdx.y << 7, bcol = blockIdx.x << 7;

  const uint16_t* ga0 = A + (size_t)(brow + (t >> 2)) * K + (t & 3) * 8;
  const uint16_t* ga1 = ga0 + (size_t)64 * K;
  const uint16_t* gb0 = B + (size_t)(bcol + (t >> 2)) * K + (t & 3) * 8;
  const uint16_t* gb1 = gb0 + (size_t)64 * K;

  f32x4 acc[4][4] = {};

  for (int k0 = 0; k0 < K; k0 += 32) {
    __syncthreads();
    gld_lds16(ga0 + k0, &As[t * 8]);
    gld_lds16(ga1 + k0, &As[2048 + t * 8]);
    gld_lds16(gb0 + k0, &Bs[t * 8]);
    gld_lds16(gb1 + k0, &Bs[2048 + t * 8]);
    __syncthreads();

    bf16x8 af[4], bfr[4];
#pragma unroll
    for (int i = 0; i < 4; ++i)
      af[i] = ldb8(&As[(wr + i * 16 + li) * 32 + lg * 8]);
#pragma unroll
    for (int i = 0; i < 4; ++i)
      bfr[i] = ldb8(&Bs[(wc + i * 16 + li) * 32 + lg * 8]);
#pragma unroll
    for (int mi = 0; mi < 4; ++mi)
#pragma unroll
      for (int ni = 0; ni < 4; ++ni)
        acc[mi][ni] = MFMA(af[mi], bfr[ni], acc[mi][ni]);
  }

#pragma unroll
  for (int mi = 0; mi < 4; ++mi) {
#pragma unroll
    for (int ni = 0; ni < 4; ++ni) {
      const int row = brow + wr + mi * 16 + lg * 4;   // + r
      const int col = bcol + wc + ni * 16 + li;
#pragma unroll
      for (int r = 0; r < 4; ++r) {
        const float v = acc[mi][ni][r];
        if (MODE == 0) {
          if (col < 1024) {
            Cq[(size_t)(row + r) * 1024 + col] = f2bf(v * 0.125f);
          } else if (col < 2048) {
            Ck[(size_t)(row + r) * 1024 + (col - 1024)] = f2bf(v);
          } else {
            const int c = col - 2048;                 // h*64 + d
            const int m = row + r;                    // b*2048 + s
            Cvt[((size_t)c + (size_t)((m >> 11) << 10)) * 2048 + (m & 2047)] = f2bf(v);
          }
        } else {
          Cf[(size_t)(row + r) * 1024 + col] = v + bias[col];
        }
      }
    }
  }
}

// ---------------------------------------------------------------- flash attention
// Swapped-operand flash attention: each lane owns ONE q-row (q = li) so the
// softmax state (m, l) and rescale are lane-local; cross-lane only for the
// max/sum reduce across the 4 lg-groups (2 shfl_xor each).
// Q,K: (4096 x 1024) bf16 (Q pre-scaled 1/8). Vt: (b,h,d,s) bf16.
__global__ __launch_bounds__(256) void attn_fwd(const uint16_t* __restrict__ Q,
                                                const uint16_t* __restrict__ K,
                                                const uint16_t* __restrict__ Vt,
                                                uint16_t* __restrict__ ctx) {
  const int bh = blockIdx.x;           // 0..31
  const int qb = 31 - blockIdx.y;      // heavy q-blocks dispatched first
  const int b  = bh >> 4, h = bh & 15;
  const int t  = threadIdx.x;
  const int w  = t >> 6, l = t & 63;
  const int li = l & 15, lg = l >> 4;

  __shared__ uint16_t P[4][16][72];    // per-wave private P slab (row pad +8)

  const int qrow = (qb << 6) + (w << 4);
  // Q as B-operand: lane holds Q[q = li][d = lg*8 + j]
  const uint16_t* qp = Q + (size_t)(b * 2048 + qrow + li) * 1024 + h * 64 + lg * 8;
  const bf16x8 q0 = ldb8(qp);
  const bf16x8 q1 = ldb8(qp + 32);

  const uint16_t* Kbase = K + (size_t)(b * 2048 + li) * 1024 + h * 64 + lg * 8;
  const uint16_t* Vbase = Vt + (size_t)(b * 1024 + h * 64 + li) * 2048 + lg * 8;

  f32x4 o[4] = {};                     // O[d = dt*16 + lg*4 + r][q = li]
  float m_r = -1e30f, l_r = 0.f;

  for (int kt = 0; kt <= qb; ++kt) {
    const int kbase = kt << 6;
    const uint16_t* kp = Kbase + (size_t)kbase * 1024;

    // QK^T swapped: A = K (row = key = li), B = Q (col = q = li)
    // -> s[tt][r] = S[key = kbase + tt*16 + lg*4 + r][q = qrow + li]
    f32x4 s[4];
#pragma unroll
    for (int tt = 0; tt < 4; ++tt) {
      f32x4 z = {};
      z = MFMA(ldb8(kp + (size_t)tt * 16 * 1024), q0, z);
      z = MFMA(ldb8(kp + (size_t)tt * 16 * 1024 + 32), q1, z);
      s[tt] = z;
    }

    // prefetch V fragments (independent of softmax): A-operand for PV,
    // lane holds Vt[d = dt*16 + li][key = kbase + half*32 + lg*8 + j]
    bf16x8 vf[4][2];
    const uint16_t* vp = Vbase + kbase;
#pragma unroll
    for (int dt = 0; dt < 4; ++dt) {
      vf[dt][0] = ldb8(vp + (size_t)dt * 16 * 2048);
      vf[dt][1] = ldb8(vp + (size_t)dt * 16 * 2048 + 32);
    }

    if (kt == qb) {   // diagonal tile: causal mask (key > q within 64-block)
      const int qloc = (w << 4) + li;
#pragma unroll
      for (int tt = 0; tt < 4; ++tt) {
        const int key = (tt << 4) + (lg << 2);
#pragma unroll
        for (int r = 0; r < 4; ++r)
          if (key + r > qloc) s[tt][r] = -1e30f;
      }
    }

    // ---- lane-local softmax (q = li) over this lane's 16 keys + cross-lg
    float tm = -1e30f;
#pragma unroll
    for (int tt = 0; tt < 4; ++tt)
      tm = fmaxf(tm, fmaxf(fmaxf(s[tt][0], s[tt][1]), fmaxf(s[tt][2], s[tt][3])));
    tm = fmaxf(tm, __shfl_xor(tm, 16));
    tm = fmaxf(tm, __shfl_xor(tm, 32));

    const float mn = fmaxf(m_r, tm);
    const float corr = __expf(m_r - mn);
    m_r = mn;

    float sum = 0.f;
    ushort4 pk[4];
#pragma unroll
    for (int tt = 0; tt < 4; ++tt) {
      const float p0 = __expf(s[tt][0] - mn);
      const float p1 = __expf(s[tt][1] - mn);
      const float p2 = __expf(s[tt][2] - mn);
      const float p3 = __expf(s[tt][3] - mn);
      sum += (p0 + p1) + (p2 + p3);
      pk[tt].x = f2bf(p0); pk[tt].y = f2bf(p1);
      pk[tt].z = f2bf(p2); pk[tt].w = f2bf(p3);
    }
    sum += __shfl_xor(sum, 16);
    sum += __shfl_xor(sum, 32);
    l_r = l_r * corr + sum;

#pragma unroll
    for (int dt = 0; dt < 4; ++dt) {
      o[dt][0] *= corr; o[dt][1] *= corr; o[dt][2] *= corr; o[dt][3] *= corr;
    }

    // ---- P relayout: lane holds P[q=li][key = tt*16 + lg*4 + r] (4 packed)
#pragma unroll
    for (int tt = 0; tt < 4; ++tt)
      *(ushort4*)&P[w][li][(tt << 4) + (lg << 2)] = pk[tt];
    asm volatile("s_waitcnt lgkmcnt(0)" ::: "memory");

    // B-operand for PV: lane holds P[q = li][key = half*32 + lg*8 + j]
    const bf16x8 pb0 = ldb8(&P[w][li][lg * 8]);
    const bf16x8 pb1 = ldb8(&P[w][li][32 + lg * 8]);
#pragma unroll
    for (int dt = 0; dt < 4; ++dt) {
      o[dt] = MFMA(vf[dt][0], pb0, o[dt]);
      o[dt] = MFMA(vf[dt][1], pb1, o[dt]);
    }
  }

  // epilogue: lane-local 1/l, pack 4 consecutive d per store
  const float inv = 1.0f / l_r;
  const int qg = b * 2048 + qrow + li;
#pragma unroll
  for (int dt = 0; dt < 4; ++dt) {
    ushort4 ov;
    ov.x = f2bf(o[dt][0] * inv); ov.y = f2bf(o[dt][1] * inv);
    ov.z = f2bf(o[dt][2] * inv); ov.w = f2bf(o[dt][3] * inv);
    *(ushort4*)(ctx + (size_t)qg * 1024 + h * 64 + (dt << 4) + (lg << 2)) = ov;
  }
}

// ---------------------------------------------------------------- launch
extern "C" void kernel_launch(void* const* d_in, const int* in_sizes, int n_in,
                              void* d_out, int out_size, void* d_ws, size_t ws_size,
                              hipStream_t stream) {
  const float* x  = (const float*)d_in[0];
  const float* Wq = (const float*)d_in[1];
  const float* Wk = (const float*)d_in[2];
  const float* Wv = (const float*)d_in[3];
  const float* Wo = (const float*)d_in[4];
  const float* bo = (const float*)d_in[5];
  float* out = (float*)d_out;

  char* ws = (char*)d_ws;
  uint16_t* xb   = (uint16_t*)(ws);                 // 8MB (dead after QKV gemm)
  uint16_t* Wqkv = (uint16_t*)(ws + ( 8u << 20));   // 6MB: Wq|Wk|Wv contiguous
  uint16_t* Wob  = (uint16_t*)(ws + (14u << 20));   // 2MB
  uint16_t* Qb   = (uint16_t*)(ws + (16u << 20));   // 8MB
  uint16_t* Kb   = (uint16_t*)(ws + (24u << 20));   // 8MB
  uint16_t* Vt   = (uint16_t*)(ws + (32u << 20));   // 8MB
  uint16_t* Ctx  = (uint16_t*)(ws);                 // overlays xb

  cvt_f32_bf16<<<4096, 256, 0, stream>>>(x,  xb);
  cvt_f32_bf16<<<1024, 256, 0, stream>>>(Wq, Wqkv);
  cvt_f32_bf16<<<1024, 256, 0, stream>>>(Wk, Wqkv + (1u << 20));
  cvt_f32_bf16<<<1024, 256, 0, stream>>>(Wv, Wqkv + (2u << 20));
  cvt_f32_bf16<<<1024, 256, 0, stream>>>(Wo, Wob);

  // fused QKV projection: C = x * [Wq|Wk|Wv]^T, N=3072 -> 24x32 grid (3 blk/CU)
  gemm_bt<0><<<dim3(24, 32), 256, 0, stream>>>(xb, Wqkv, Qb, Kb, Vt,
                                               nullptr, nullptr, 1024);

  attn_fwd<<<dim3(32, 32), 256, 0, stream>>>(Qb, Kb, Vt, Ctx);

  // output projection + bias (fp32 out)
  gemm_bt<2><<<dim3(8, 32), 256, 0, stream>>>(Ctx, Wob, nullptr, nullptr, nullptr,
                                              out, bo, 1024);
}

// Round 3
// 136.306 us; speedup vs baseline: 1.9136x; 1.7143x over previous
//
#include <hip/hip_runtime.h>
#include <stdint.h>

#define SEQ   2048
#define DEMB  1024
#define NH    16
#define HD    64
#define MROWS 4096   // BS*SEQ

typedef __bf16 bf16x8 __attribute__((ext_vector_type(8)));
typedef float  f32x4  __attribute__((ext_vector_type(4)));

#define MFMA(a, b, c) __builtin_amdgcn_mfma_f32_16x16x32_bf16((a), (b), (c), 0, 0, 0)

static __device__ __forceinline__ uint16_t f2bf(float f) {
  uint32_t u = __float_as_uint(f);
  u += 0x7FFFu + ((u >> 16) & 1u);   // RNE
  return (uint16_t)(u >> 16);
}

static __device__ __forceinline__ bf16x8 ldb8(const uint16_t* p) {
  union { uint4 i; bf16x8 b; } u;
  u.i = *(const uint4*)p;
  return u.b;
}

static __device__ __forceinline__ void gld_lds16(const uint16_t* g, uint16_t* l) {
  __builtin_amdgcn_global_load_lds(
      (const __attribute__((address_space(1))) uint32_t*)(g),
      (__attribute__((address_space(3))) uint32_t*)(l),
      16, 0, 0);
}

// ---------------------------------------------------------------- converts
__global__ __launch_bounds__(256) void cvt_f32_bf16(const float* __restrict__ in,
                                                    uint16_t* __restrict__ out) {
  int i = (blockIdx.x * 256 + threadIdx.x) * 4;
  float4 v = *(const float4*)(in + i);
  ushort4 o;
  o.x = f2bf(v.x); o.y = f2bf(v.y); o.z = f2bf(v.z); o.w = f2bf(v.w);
  *(ushort4*)(out + i) = o;
}

// ---------------------------------------------------------------- GEMM C = A * B^T
// A: MxK bf16 row-major, B: NxK bf16 row-major (m97 structure, 128x128 tile).
// MODE 0: fused QKV epilogue (N=3072): cols [0,1024) -> Q (scaled 1/8),
//         [1024,2048) -> K, [2048,3072) -> V transposed per head (b,h,d,s).
// MODE 2: fp32 out + bias (out projection).
template <int MODE>
__global__ __launch_bounds__(256) void gemm_bt(const uint16_t* __restrict__ A,
                                               const uint16_t* __restrict__ B,
                                               uint16_t* __restrict__ Cq,
                                               uint16_t* __restrict__ Ck,
                                               uint16_t* __restrict__ Cvt,
                                               float* __restrict__ Cf,
                                               const float* __restrict__ bias,
                                               int K) {
  __shared__ uint16_t As[128 * 32];
  __shared__ uint16_t Bs[128 * 32];
  const int t  = threadIdx.x;
  const int l  = t & 63;
  const int li = l & 15, lg = l >> 4;
  const int w  = t >> 6;
  const int wr = (w >> 1) << 6, wc = (w & 1) << 6;
  const int brow = blockIdx.y << 7, bcol = blockIdx.x << 7;

  const uint16_t* ga0 = A + (size_t)(brow + (t >> 2)) * K + (t & 3) * 8;
  const uint16_t* ga1 = ga0 + (size_t)64 * K;
  const uint16_t* gb0 = B + (size_t)(bcol + (t >> 2)) * K + (t & 3) * 8;
  const uint16_t* gb1 = gb0 + (size_t)64 * K;

  f32x4 acc[4][4] = {};

  for (int k0 = 0; k0 < K; k0 += 32) {
    __syncthreads();
    gld_lds16(ga0 + k0, &As[t * 8]);
    gld_lds16(ga1 + k0, &As[2048 + t * 8]);
    gld_lds16(gb0 + k0, &Bs[t * 8]);
    gld_lds16(gb1 + k0, &Bs[2048 + t * 8]);
    __syncthreads();

    bf16x8 af[4], bfr[4];
#pragma unroll
    for (int i = 0; i < 4; ++i)
      af[i] = ldb8(&As[(wr + i * 16 + li) * 32 + lg * 8]);
#pragma unroll
    for (int i = 0; i < 4; ++i)
      bfr[i] = ldb8(&Bs[(wc + i * 16 + li) * 32 + lg * 8]);
#pragma unroll
    for (int mi = 0; mi < 4; ++mi)
#pragma unroll
      for (int ni = 0; ni < 4; ++ni)
        acc[mi][ni] = MFMA(af[mi], bfr[ni], acc[mi][ni]);
  }

#pragma unroll
  for (int mi = 0; mi < 4; ++mi) {
#pragma unroll
    for (int ni = 0; ni < 4; ++ni) {
      const int row = brow + wr + mi * 16 + lg * 4;   // + r
      const int col = bcol + wc + ni * 16 + li;
#pragma unroll
      for (int r = 0; r < 4; ++r) {
        const float v = acc[mi][ni][r];
        if (MODE == 0) {
          if (col < 1024) {
            Cq[(size_t)(row + r) * 1024 + col] = f2bf(v * 0.125f);
          } else if (col < 2048) {
            Ck[(size_t)(row + r) * 1024 + (col - 1024)] = f2bf(v);
          } else {
            const int c = col - 2048;                 // h*64 + d
            const int m = row + r;                    // b*2048 + s
            Cvt[((size_t)c + (size_t)((m >> 11) << 10)) * 2048 + (m & 2047)] = f2bf(v);
          }
        } else {
          Cf[(size_t)(row + r) * 1024 + col] = v + bias[col];
        }
      }
    }
  }
}

// ---------------------------------------------------------------- flash attention
// Swapped-operand flash attention with LDS-staged, double-buffered K/V tiles.
// Each block: 64 q-rows (4 waves x 16), loops over 64-key tiles.
// K/V tiles staged via global_load_lds with PRE-SWIZZLED global source
// (XOR col ^= (row&7)*16B) so swizzled ds_reads are ~2-way-conflict only.
// Q,K: (4096 x 1024) bf16 (Q pre-scaled 1/8). Vt: (b,h,d,s) bf16.
__global__ __launch_bounds__(256) void attn_fwd(const uint16_t* __restrict__ Q,
                                                const uint16_t* __restrict__ K,
                                                const uint16_t* __restrict__ Vt,
                                                uint16_t* __restrict__ ctx) {
  const int bh = blockIdx.x;           // 0..31
  const int qb = 31 - blockIdx.y;      // heavy q-blocks dispatched first
  const int b  = bh >> 4, h = bh & 15;
  const int t  = threadIdx.x;
  const int w  = t >> 6, l = t & 63;
  const int li = l & 15, lg = l >> 4;

  __shared__ uint16_t Kl[2][64 * 64];  // 8KB x2, swizzled rows (key, d)
  __shared__ uint16_t Vl[2][64 * 64];  // 8KB x2, swizzled rows (d, key)
  __shared__ uint16_t P[4][16][72];    // per-wave P slab (stride 144B, 16B-aligned)

  const uint16_t* Kg = K + (size_t)(b * 2048) * 1024 + h * 64;   // key-row 0
  const uint16_t* Vg = Vt + (size_t)(b * 1024 + h * 64) * 2048;  // d-row 0

  // staging geometry: 8 threads/row, 32 rows/call, 2 calls per tile
  const int srow = t >> 3;                          // 0..31
  const int ssw  = (srow & 7) * 8;                  // swizzle (u16 units)
  const int scol = ((t & 7) * 8) ^ ssw;             // pre-swizzled source col

  const int qrow = (qb << 6) + (w << 4);
  // Q as B-operand: lane holds Q[q = li][d = lg*8 + j]
  const uint16_t* qp = Q + (size_t)(b * 2048 + qrow + li) * 1024 + h * 64 + lg * 8;
  const bf16x8 q0 = ldb8(qp);
  const bf16x8 q1 = ldb8(qp + 32);

  f32x4 o[4] = {};                     // O[d = dt*16 + lg*4 + r][q = li]
  float m_r = -1e30f, l_r = 0.f;

  auto stage = [&](int buf, int kt2) {
    const int kb2 = kt2 << 6;
    gld_lds16(Kg + (size_t)(kb2 + srow) * 1024 + scol,        &Kl[buf][t * 8]);
    gld_lds16(Kg + (size_t)(kb2 + 32 + srow) * 1024 + scol,   &Kl[buf][2048 + t * 8]);
    gld_lds16(Vg + (size_t)srow * 2048 + kb2 + scol,          &Vl[buf][t * 8]);
    gld_lds16(Vg + (size_t)(32 + srow) * 2048 + kb2 + scol,   &Vl[buf][2048 + t * 8]);
  };

  stage(0, 0);
  __syncthreads();                     // drain prologue staging
  int cur = 0;

  const int fsw = (li & 7) * 8;        // fragment-read swizzle (u16 units)

  for (int kt = 0; kt <= qb; ++kt) {
    if (kt < qb) stage(cur ^ 1, kt + 1);   // prefetch next tile (in flight all iter)

    const uint16_t* Kc = &Kl[cur][0];
    const uint16_t* Vc = &Vl[cur][0];

    // QK^T swapped: A = K (row = key), B = Q (col = q = li)
    // s[tt][r] = S[key = kt*64 + tt*16 + lg*4 + r][q = qrow + li]
    f32x4 s[4];
#pragma unroll
    for (int tt = 0; tt < 4; ++tt) {
      const uint16_t* kr = Kc + (tt * 16 + li) * 64;
      f32x4 z = {};
      z = MFMA(ldb8(kr + ((lg * 8) ^ fsw)), q0, z);
      z = MFMA(ldb8(kr + ((32 + lg * 8) ^ fsw)), q1, z);
      s[tt] = z;
    }

    // V fragments (independent of softmax): A-operand for PV,
    // lane holds V[d = dt*16 + li][key = half*32 + lg*8 + j]
    bf16x8 vf[4][2];
#pragma unroll
    for (int dt = 0; dt < 4; ++dt) {
      const uint16_t* vr = Vc + (dt * 16 + li) * 64;
      vf[dt][0] = ldb8(vr + ((lg * 8) ^ fsw));
      vf[dt][1] = ldb8(vr + ((32 + lg * 8) ^ fsw));
    }

    if (kt == qb) {   // diagonal tile: causal mask (key > q within 64-block)
      const int qloc = (w << 4) + li;
#pragma unroll
      for (int tt = 0; tt < 4; ++tt) {
        const int key = (tt << 4) + (lg << 2);
#pragma unroll
        for (int r = 0; r < 4; ++r)
          if (key + r > qloc) s[tt][r] = -1e30f;
      }
    }

    // ---- lane-local softmax (q = li) over this lane's 16 keys + cross-lg
    float tm = -1e30f;
#pragma unroll
    for (int tt = 0; tt < 4; ++tt)
      tm = fmaxf(tm, fmaxf(fmaxf(s[tt][0], s[tt][1]), fmaxf(s[tt][2], s[tt][3])));
    tm = fmaxf(tm, __shfl_xor(tm, 16));
    tm = fmaxf(tm, __shfl_xor(tm, 32));

    const float mn = fmaxf(m_r, tm);
    const float corr = __expf(m_r - mn);
    m_r = mn;

    float sum = 0.f;
    ushort4 pk[4];
#pragma unroll
    for (int tt = 0; tt < 4; ++tt) {
      const float p0 = __expf(s[tt][0] - mn);
      const float p1 = __expf(s[tt][1] - mn);
      const float p2 = __expf(s[tt][2] - mn);
      const float p3 = __expf(s[tt][3] - mn);
      sum += (p0 + p1) + (p2 + p3);
      pk[tt].x = f2bf(p0); pk[tt].y = f2bf(p1);
      pk[tt].z = f2bf(p2); pk[tt].w = f2bf(p3);
    }
    sum += __shfl_xor(sum, 16);
    sum += __shfl_xor(sum, 32);
    l_r = l_r * corr + sum;

#pragma unroll
    for (int dt = 0; dt < 4; ++dt) {
      o[dt][0] *= corr; o[dt][1] *= corr; o[dt][2] *= corr; o[dt][3] *= corr;
    }

    // ---- P relayout: lane holds P[q=li][key = tt*16 + lg*4 + r]
#pragma unroll
    for (int tt = 0; tt < 4; ++tt)
      *(ushort4*)&P[w][li][(tt << 4) + (lg << 2)] = pk[tt];
    asm volatile("s_waitcnt lgkmcnt(0)" ::: "memory");

    // B-operand for PV: lane holds P[q = li][key = half*32 + lg*8 + j]
    const bf16x8 pb0 = ldb8(&P[w][li][lg * 8]);
    const bf16x8 pb1 = ldb8(&P[w][li][32 + lg * 8]);
#pragma unroll
    for (int dt = 0; dt < 4; ++dt) {
      o[dt] = MFMA(vf[dt][0], pb0, o[dt]);
      o[dt] = MFMA(vf[dt][1], pb1, o[dt]);
    }

    __syncthreads();   // drains staging vmcnt + releases buf for next overwrite
    cur ^= 1;
  }

  // epilogue: lane-local 1/l, pack 4 consecutive d per store
  const float inv = 1.0f / l_r;
  const int qg = b * 2048 + qrow + li;
#pragma unroll
  for (int dt = 0; dt < 4; ++dt) {
    ushort4 ov;
    ov.x = f2bf(o[dt][0] * inv); ov.y = f2bf(o[dt][1] * inv);
    ov.z = f2bf(o[dt][2] * inv); ov.w = f2bf(o[dt][3] * inv);
    *(ushort4*)(ctx + (size_t)qg * 1024 + h * 64 + (dt << 4) + (lg << 2)) = ov;
  }
}

// ---------------------------------------------------------------- launch
extern "C" void kernel_launch(void* const* d_in, const int* in_sizes, int n_in,
                              void* d_out, int out_size, void* d_ws, size_t ws_size,
                              hipStream_t stream) {
  const float* x  = (const float*)d_in[0];
  const float* Wq = (const float*)d_in[1];
  const float* Wk = (const float*)d_in[2];
  const float* Wv = (const float*)d_in[3];
  const float* Wo = (const float*)d_in[4];
  const float* bo = (const float*)d_in[5];
  float* out = (float*)d_out;

  char* ws = (char*)d_ws;
  uint16_t* xb   = (uint16_t*)(ws);                 // 8MB (dead after QKV gemm)
  uint16_t* Wqkv = (uint16_t*)(ws + ( 8u << 20));   // 6MB: Wq|Wk|Wv contiguous
  uint16_t* Wob  = (uint16_t*)(ws + (14u << 20));   // 2MB
  uint16_t* Qb   = (uint16_t*)(ws + (16u << 20));   // 8MB
  uint16_t* Kb   = (uint16_t*)(ws + (24u << 20));   // 8MB
  uint16_t* Vt   = (uint16_t*)(ws + (32u << 20));   // 8MB
  uint16_t* Ctx  = (uint16_t*)(ws);                 // overlays xb

  cvt_f32_bf16<<<4096, 256, 0, stream>>>(x,  xb);
  cvt_f32_bf16<<<1024, 256, 0, stream>>>(Wq, Wqkv);
  cvt_f32_bf16<<<1024, 256, 0, stream>>>(Wk, Wqkv + (1u << 20));
  cvt_f32_bf16<<<1024, 256, 0, stream>>>(Wv, Wqkv + (2u << 20));
  cvt_f32_bf16<<<1024, 256, 0, stream>>>(Wo, Wob);

  // fused QKV projection: C = x * [Wq|Wk|Wv]^T, N=3072 -> 24x32 grid (3 blk/CU)
  gemm_bt<0><<<dim3(24, 32), 256, 0, stream>>>(xb, Wqkv, Qb, Kb, Vt,
                                               nullptr, nullptr, 1024);

  attn_fwd<<<dim3(32, 32), 256, 0, stream>>>(Qb, Kb, Vt, Ctx);

  // output projection + bias (fp32 out)
  gemm_bt<2><<<dim3(8, 32), 256, 0, stream>>>(Ctx, Wob, nullptr, nullptr, nullptr,
                                              out, bo, 1024);
}

// Round 4
// 115.407 us; speedup vs baseline: 2.2601x; 1.1811x over previous
//
#include <hip/hip_runtime.h>
#include <stdint.h>

#define SEQ   2048
#define DEMB  1024
#define NH    16
#define HD    64
#define MROWS 4096   // BS*SEQ

typedef __bf16 bf16x8 __attribute__((ext_vector_type(8)));
typedef __bf16 bf16x4 __attribute__((ext_vector_type(4)));
typedef float  f32x4  __attribute__((ext_vector_type(4)));

#define MFMA(a, b, c) __builtin_amdgcn_mfma_f32_16x16x32_bf16((a), (b), (c), 0, 0, 0)

// scalar f32->bf16 via compiler cast (RNE, emits v_cvt_*_bf16_f32)
static __device__ __forceinline__ uint16_t f2bf(float f) {
  union { __bf16 b; uint16_t u; } c;
  c.b = (__bf16)f;
  return c.u;
}

// pack 4 f32 -> 4 bf16 (compiler pairs into v_cvt_pk_bf16_f32)
static __device__ __forceinline__ ushort4 pack4(f32x4 f) {
  union { bf16x4 b; ushort4 u; } c;
  c.b[0] = (__bf16)f[0]; c.b[1] = (__bf16)f[1];
  c.b[2] = (__bf16)f[2]; c.b[3] = (__bf16)f[3];
  return c.u;
}

static __device__ __forceinline__ bf16x8 ldb8(const uint16_t* p) {
  union { uint4 i; bf16x8 b; } u;
  u.i = *(const uint4*)p;
  return u.b;
}

static __device__ __forceinline__ void gld_lds16(const uint16_t* g, uint16_t* l) {
  __builtin_amdgcn_global_load_lds(
      (const __attribute__((address_space(1))) uint32_t*)(g),
      (__attribute__((address_space(3))) uint32_t*)(l),
      16, 0, 0);
}

// ---------------------------------------------------------------- fused converts
// blocks [0,4096): x -> xb ; [4096,5120): Wq ; [5120,6144): Wk ;
// [6144,7168): Wv ; [7168,8192): Wo
__global__ __launch_bounds__(256) void cvt_all(const float* __restrict__ x,
                                               const float* __restrict__ wq,
                                               const float* __restrict__ wk,
                                               const float* __restrict__ wv,
                                               const float* __restrict__ wo,
                                               uint16_t* __restrict__ xb,
                                               uint16_t* __restrict__ wqkv,
                                               uint16_t* __restrict__ wob) {
  const int bid = blockIdx.x;
  const float* src; uint16_t* dst; int off;
  if (bid < 4096)      { src = x;  dst = xb;                 off = bid; }
  else if (bid < 5120) { src = wq; dst = wqkv;               off = bid - 4096; }
  else if (bid < 6144) { src = wk; dst = wqkv + (1u << 20);  off = bid - 5120; }
  else if (bid < 7168) { src = wv; dst = wqkv + (2u << 20);  off = bid - 6144; }
  else                 { src = wo; dst = wob;                off = bid - 7168; }
  const int i = (off * 256 + threadIdx.x) * 4;
  float4 v = *(const float4*)(src + i);
  f32x4 f; f[0] = v.x; f[1] = v.y; f[2] = v.z; f[3] = v.w;
  *(ushort4*)(dst + i) = pack4(f);
}

// ---------------------------------------------------------------- GEMM C = A * B^T
// Double-buffered LDS, stage(k+1) issued before compute(k), one barrier/iter.
// MODE 0: BN=128, fused QKV epilogue (N=3072): cols [0,1024) -> Q (scaled
//         0.125*log2e), [1024,2048) -> K, [2048,3072) -> V^T per head (b,h,d,s).
// MODE 2: BN=64, fp32 out + bias (out projection), grid.x = 16 (512 blocks).
template <int MODE>
__global__ __launch_bounds__(256) void gemm_bt(const uint16_t* __restrict__ A,
                                               const uint16_t* __restrict__ B,
                                               uint16_t* __restrict__ Cq,
                                               uint16_t* __restrict__ Ck,
                                               uint16_t* __restrict__ Cvt,
                                               float* __restrict__ Cf,
                                               const float* __restrict__ bias,
                                               int K) {
  constexpr int BN = (MODE == 2) ? 64 : 128;
  constexpr int NI = (MODE == 2) ? 2 : 4;      // per-wave N fragments
  __shared__ uint16_t As[2][128 * 32];
  __shared__ uint16_t Bs[2][BN * 32];
  const int t  = threadIdx.x;
  const int l  = t & 63;
  const int li = l & 15, lg = l >> 4;
  const int w  = t >> 6;
  const int wr = (w >> 1) << 6;
  const int wc = (MODE == 2) ? ((w & 1) << 5) : ((w & 1) << 6);
  const int brow = blockIdx.y << 7;
  const int bcol = blockIdx.x * BN;

  const uint16_t* ga0 = A + (size_t)(brow + (t >> 2)) * K + (t & 3) * 8;
  const uint16_t* ga1 = ga0 + (size_t)64 * K;
  const uint16_t* gb0 = B + (size_t)(bcol + (t >> 2)) * K + (t & 3) * 8;
  const uint16_t* gb1 = gb0 + (size_t)64 * K;   // unused when BN==64

  auto stage = [&](int buf, int k0) {
    gld_lds16(ga0 + k0, &As[buf][t * 8]);
    gld_lds16(ga1 + k0, &As[buf][2048 + t * 8]);
    gld_lds16(gb0 + k0, &Bs[buf][t * 8]);
    if (BN == 128) gld_lds16(gb1 + k0, &Bs[buf][2048 + t * 8]);
  };

  f32x4 acc[4][NI] = {};

  stage(0, 0);
  __syncthreads();
  int cur = 0;

  for (int k0 = 0; k0 < K; k0 += 32) {
    if (k0 + 32 < K) stage(cur ^ 1, k0 + 32);   // in flight during compute

    bf16x8 af[4], bfr[NI];
#pragma unroll
    for (int i = 0; i < 4; ++i)
      af[i] = ldb8(&As[cur][(wr + i * 16 + li) * 32 + lg * 8]);
#pragma unroll
    for (int i = 0; i < NI; ++i)
      bfr[i] = ldb8(&Bs[cur][(wc + i * 16 + li) * 32 + lg * 8]);
#pragma unroll
    for (int mi = 0; mi < 4; ++mi)
#pragma unroll
      for (int ni = 0; ni < NI; ++ni)
        acc[mi][ni] = MFMA(af[mi], bfr[ni], acc[mi][ni]);

    __syncthreads();   // drains staging vmcnt + protects buffer reuse
    cur ^= 1;
  }

#pragma unroll
  for (int mi = 0; mi < 4; ++mi) {
#pragma unroll
    for (int ni = 0; ni < NI; ++ni) {
      const int row = brow + wr + mi * 16 + lg * 4;   // + r
      const int col = bcol + wc + ni * 16 + li;
#pragma unroll
      for (int r = 0; r < 4; ++r) {
        const float v = acc[mi][ni][r];
        if (MODE == 0) {
          if (col < 1024) {
            // Q scaled by 1/sqrt(64) * log2(e) for exp2-domain softmax
            Cq[(size_t)(row + r) * 1024 + col] = f2bf(v * 0.18033688f);
          } else if (col < 2048) {
            Ck[(size_t)(row + r) * 1024 + (col - 1024)] = f2bf(v);
          } else {
            const int c = col - 2048;                 // h*64 + d
            const int m = row + r;                    // b*2048 + s
            Cvt[((size_t)c + (size_t)((m >> 11) << 10)) * 2048 + (m & 2047)] = f2bf(v);
          }
        } else {
          Cf[(size_t)(row + r) * 1024 + col] = v + bias[col];
        }
      }
    }
  }
}

// ---------------------------------------------------------------- flash attention
// Swapped-operand flash attention, LDS-staged double-buffered K/V (pre-swizzled
// source + swizzled reads), exp2-domain softmax (Q pre-scaled by log2e/8),
// defer-max (T13, THR=8 in log2 domain).
__global__ __launch_bounds__(256) void attn_fwd(const uint16_t* __restrict__ Q,
                                                const uint16_t* __restrict__ K,
                                                const uint16_t* __restrict__ Vt,
                                                uint16_t* __restrict__ ctx) {
  const int bh = blockIdx.x;           // 0..31
  const int qb = 31 - blockIdx.y;      // heavy q-blocks dispatched first
  const int b  = bh >> 4, h = bh & 15;
  const int t  = threadIdx.x;
  const int w  = t >> 6, l = t & 63;
  const int li = l & 15, lg = l >> 4;

  __shared__ uint16_t Kl[2][64 * 64];  // 8KB x2, swizzled rows (key, d)
  __shared__ uint16_t Vl[2][64 * 64];  // 8KB x2, swizzled rows (d, key)
  __shared__ uint16_t P[4][16][72];    // per-wave P slab

  const uint16_t* Kg = K + (size_t)(b * 2048) * 1024 + h * 64;
  const uint16_t* Vg = Vt + (size_t)(b * 1024 + h * 64) * 2048;

  const int srow = t >> 3;                          // 0..31
  const int scol = ((t & 7) * 8) ^ ((srow & 7) * 8);

  const int qrow = (qb << 6) + (w << 4);
  const uint16_t* qp = Q + (size_t)(b * 2048 + qrow + li) * 1024 + h * 64 + lg * 8;
  const bf16x8 q0 = ldb8(qp);
  const bf16x8 q1 = ldb8(qp + 32);

  f32x4 o[4] = {};                     // O[d = dt*16 + lg*4 + r][q = li]
  float m_r = -1e30f, l_r = 0.f;

  auto stage = [&](int buf, int kt2) {
    const int kb2 = kt2 << 6;
    gld_lds16(Kg + (size_t)(kb2 + srow) * 1024 + scol,      &Kl[buf][t * 8]);
    gld_lds16(Kg + (size_t)(kb2 + 32 + srow) * 1024 + scol, &Kl[buf][2048 + t * 8]);
    gld_lds16(Vg + (size_t)srow * 2048 + kb2 + scol,        &Vl[buf][t * 8]);
    gld_lds16(Vg + (size_t)(32 + srow) * 2048 + kb2 + scol, &Vl[buf][2048 + t * 8]);
  };

  stage(0, 0);
  __syncthreads();
  int cur = 0;

  const int fsw = (li & 7) * 8;        // fragment-read swizzle (u16 units)

  for (int kt = 0; kt <= qb; ++kt) {
    if (kt < qb) stage(cur ^ 1, kt + 1);

    const uint16_t* Kc = &Kl[cur][0];
    const uint16_t* Vc = &Vl[cur][0];

    // QK^T swapped: s[tt][r] = S[key = kt*64+tt*16+lg*4+r][q = qrow+li] (log2 dom)
    f32x4 s[4];
#pragma unroll
    for (int tt = 0; tt < 4; ++tt) {
      const uint16_t* kr = Kc + (tt * 16 + li) * 64;
      f32x4 z = {};
      z = MFMA(ldb8(kr + ((lg * 8) ^ fsw)), q0, z);
      z = MFMA(ldb8(kr + ((32 + lg * 8) ^ fsw)), q1, z);
      s[tt] = z;
    }

    // V fragments: lane holds V[d = dt*16 + li][key = half*32 + lg*8 + j]
    bf16x8 vf[4][2];
#pragma unroll
    for (int dt = 0; dt < 4; ++dt) {
      const uint16_t* vr = Vc + (dt * 16 + li) * 64;
      vf[dt][0] = ldb8(vr + ((lg * 8) ^ fsw));
      vf[dt][1] = ldb8(vr + ((32 + lg * 8) ^ fsw));
    }

    if (kt == qb) {   // diagonal tile: causal mask
      const int qloc = (w << 4) + li;
#pragma unroll
      for (int tt = 0; tt < 4; ++tt) {
        const int key = (tt << 4) + (lg << 2);
#pragma unroll
        for (int r = 0; r < 4; ++r)
          if (key + r > qloc) s[tt][r] = -1e30f;
      }
    }

    // ---- tile max (per q-row = li), cross-lg reduce
    float tm = fmaxf(fmaxf(s[0][0], s[0][1]), fmaxf(s[0][2], s[0][3]));
#pragma unroll
    for (int tt = 1; tt < 4; ++tt)
      tm = fmaxf(tm, fmaxf(fmaxf(s[tt][0], s[tt][1]), fmaxf(s[tt][2], s[tt][3])));
    tm = fmaxf(tm, __shfl_xor(tm, 16));
    tm = fmaxf(tm, __shfl_xor(tm, 32));

    // ---- defer-max (T13): skip rescale when max growth <= 8 (log2 domain)
    if (!__all(tm - m_r <= 8.f)) {
      const float mn = fmaxf(m_r, tm);
      const float corr = __builtin_amdgcn_exp2f(m_r - mn);
      m_r = mn;
      l_r *= corr;
#pragma unroll
      for (int dt = 0; dt < 4; ++dt) {
        o[dt][0] *= corr; o[dt][1] *= corr; o[dt][2] *= corr; o[dt][3] *= corr;
      }
    }

    float sum = 0.f;
    ushort4 pk[4];
#pragma unroll
    for (int tt = 0; tt < 4; ++tt) {
      f32x4 p;
      p[0] = __builtin_amdgcn_exp2f(s[tt][0] - m_r);
      p[1] = __builtin_amdgcn_exp2f(s[tt][1] - m_r);
      p[2] = __builtin_amdgcn_exp2f(s[tt][2] - m_r);
      p[3] = __builtin_amdgcn_exp2f(s[tt][3] - m_r);
      sum += (p[0] + p[1]) + (p[2] + p[3]);
      pk[tt] = pack4(p);
    }
    sum += __shfl_xor(sum, 16);
    sum += __shfl_xor(sum, 32);
    l_r += sum;

    // ---- P relayout: lane holds P[q=li][key = tt*16 + lg*4 + r]
#pragma unroll
    for (int tt = 0; tt < 4; ++tt)
      *(ushort4*)&P[w][li][(tt << 4) + (lg << 2)] = pk[tt];
    asm volatile("s_waitcnt lgkmcnt(0)" ::: "memory");

    const bf16x8 pb0 = ldb8(&P[w][li][lg * 8]);
    const bf16x8 pb1 = ldb8(&P[w][li][32 + lg * 8]);
#pragma unroll
    for (int dt = 0; dt < 4; ++dt) {
      o[dt] = MFMA(vf[dt][0], pb0, o[dt]);
      o[dt] = MFMA(vf[dt][1], pb1, o[dt]);
    }

    __syncthreads();
    cur ^= 1;
  }

  // epilogue
  const float inv = 1.0f / l_r;
  const int qg = b * 2048 + qrow + li;
#pragma unroll
  for (int dt = 0; dt < 4; ++dt) {
    f32x4 ov = o[dt];
    ov[0] *= inv; ov[1] *= inv; ov[2] *= inv; ov[3] *= inv;
    *(ushort4*)(ctx + (size_t)qg * 1024 + h * 64 + (dt << 4) + (lg << 2)) = pack4(ov);
  }
}

// ---------------------------------------------------------------- launch
extern "C" void kernel_launch(void* const* d_in, const int* in_sizes, int n_in,
                              void* d_out, int out_size, void* d_ws, size_t ws_size,
                              hipStream_t stream) {
  const float* x  = (const float*)d_in[0];
  const float* Wq = (const float*)d_in[1];
  const float* Wk = (const float*)d_in[2];
  const float* Wv = (const float*)d_in[3];
  const float* Wo = (const float*)d_in[4];
  const float* bo = (const float*)d_in[5];
  float* out = (float*)d_out;

  char* ws = (char*)d_ws;
  uint16_t* xb   = (uint16_t*)(ws);                 // 8MB (dead after QKV gemm)
  uint16_t* Wqkv = (uint16_t*)(ws + ( 8u << 20));   // 6MB: Wq|Wk|Wv contiguous
  uint16_t* Wob  = (uint16_t*)(ws + (14u << 20));   // 2MB
  uint16_t* Qb   = (uint16_t*)(ws + (16u << 20));   // 8MB
  uint16_t* Kb   = (uint16_t*)(ws + (24u << 20));   // 8MB
  uint16_t* Vt   = (uint16_t*)(ws + (32u << 20));   // 8MB
  uint16_t* Ctx  = (uint16_t*)(ws);                 // overlays xb

  cvt_all<<<8192, 256, 0, stream>>>(x, Wq, Wk, Wv, Wo, xb, Wqkv, Wob);

  // fused QKV projection: C = x * [Wq|Wk|Wv]^T, N=3072 -> 24x32 grid (3 blk/CU)
  gemm_bt<0><<<dim3(24, 32), 256, 0, stream>>>(xb, Wqkv, Qb, Kb, Vt,
                                               nullptr, nullptr, 1024);

  attn_fwd<<<dim3(32, 32), 256, 0, stream>>>(Qb, Kb, Vt, Ctx);

  // output projection + bias (fp32 out), BN=64 -> 16x32 grid (2 blk/CU)
  gemm_bt<2><<<dim3(16, 32), 256, 0, stream>>>(Ctx, Wob, nullptr, nullptr, nullptr,
                                               out, bo, 1024);
}